// Round 5
// baseline (135.185 us; speedup 1.0000x reference)
//
#include <hip/hip_runtime.h>
#include <math.h>

#define NP 8      // paths
#define ND 128    // D = c / P
#define NC 1024   // channels = NP*ND
#define NL 4096   // sequence length
#define NB 16     // batch
#define LN_EPS 1e-5f

typedef float v4f __attribute__((ext_vector_type(4)));

// ---------------- Kernel 1: global average pool over l ----------------
// One WAVE per (b,channel) row: 4096 blocks x 256 threads (4 waves/block).
// Sweeps x FORWARD (row 0 .. 16383), allocating x into L3.
__global__ __launch_bounds__(256) void pool_kernel(const float* __restrict__ x,
                                                   float* __restrict__ y) {
    const int wid  = threadIdx.x >> 6;
    const int lane = threadIdx.x & 63;
    const int row  = blockIdx.x * 4 + wid;          // 0 .. NB*NC-1
    const v4f* xr = (const v4f*)(x + (size_t)row * NL);
    float s = 0.f;
    #pragma unroll
    for (int i = 0; i < 16; ++i) {                  // 16*64 = 1024 float4 = row
        v4f v = xr[lane + i * 64];
        s += v.x + v.y + v.z + v.w;
    }
    #pragma unroll
    for (int off = 32; off; off >>= 1) s += __shfl_down(s, off, 64);
    if (lane == 0) y[row] = s * (1.f / NL);
}

// ---------------- Kernel 2: attn + gate -> scale ----------------
// One block per batch. 1024 threads = one per (p,d).
__global__ __launch_bounds__(1024) void attn_kernel(
    const float* __restrict__ y,
    const float* __restrict__ conv1_w,   // (NP,5)
    const float* __restrict__ conv2_w,   // (NP,9)
    const float* __restrict__ combine_w, // (2,)
    const float* __restrict__ combine_b, // scalar
    const float* __restrict__ ln_g, const float* __restrict__ ln_b,
    const float* __restrict__ W1, const float* __restrict__ b1,  // (NP,2NP),(2NP)
    const float* __restrict__ W2, const float* __restrict__ b2,  // (2NP,NP),(NP)
    float* __restrict__ scale)
{
    const int b = blockIdx.x;
    const int tid = threadIdx.x;
    const int p = tid >> 7;      // path
    const int d = tid & 127;     // position in D

    __shared__ float sy[NC];
    __shared__ float sattn[NC];
    __shared__ float sred[16];
    __shared__ float sgate[NP];

    sy[tid] = y[b * NC + tid];
    __syncthreads();

    const float* rowp = sy + p * ND;
    float c1 = 0.f;
    #pragma unroll
    for (int t = 0; t < 5; ++t) {
        int dd = d + t - 2;
        float v = (dd >= 0 && dd < ND) ? rowp[dd] : 0.f;
        c1 += conv1_w[p * 5 + t] * v;
    }
    float c2 = 0.f;
    #pragma unroll
    for (int t = 0; t < 9; ++t) {
        int dd = d + t - 4;
        float v = (dd >= 0 && dd < ND) ? rowp[dd] : 0.f;
        c2 += conv2_w[p * 9 + t] * v;
    }
    const float z = combine_w[0] * c1 + combine_w[1] * c2 + combine_b[0];
    const float a = 1.f / (1.f + expf(-z));
    sattn[tid] = a;

    // per-path mean of attn: each path = 2 consecutive waves of 64
    float r = a;
    #pragma unroll
    for (int off = 32; off; off >>= 1) r += __shfl_down(r, off, 64);
    const int lane = tid & 63, wid = tid >> 6;
    if (lane == 0) sred[wid] = r;
    __syncthreads();

    if (tid == 0) {
        float cross[NP];
        #pragma unroll
        for (int pp = 0; pp < NP; ++pp)
            cross[pp] = (sred[2 * pp] + sred[2 * pp + 1]) * (1.f / ND);
        float mu = 0.f;
        #pragma unroll
        for (int pp = 0; pp < NP; ++pp) mu += cross[pp];
        mu *= (1.f / NP);
        float var = 0.f;
        #pragma unroll
        for (int pp = 0; pp < NP; ++pp) { float dl = cross[pp] - mu; var += dl * dl; }
        var *= (1.f / NP);
        const float inv = rsqrtf(var + LN_EPS);
        float h[NP];
        #pragma unroll
        for (int pp = 0; pp < NP; ++pp)
            h[pp] = (cross[pp] - mu) * inv * ln_g[pp] + ln_b[pp];
        float h2[2 * NP];
        for (int j = 0; j < 2 * NP; ++j) {
            float s = b1[j];
            #pragma unroll
            for (int pp = 0; pp < NP; ++pp) s += h[pp] * W1[pp * (2 * NP) + j];
            h2[j] = 0.5f * s * (1.f + erff(s * 0.70710678118654752f));  // exact GELU
        }
        for (int pp = 0; pp < NP; ++pp) {
            float s = b2[pp];
            #pragma unroll
            for (int j = 0; j < 2 * NP; ++j) s += h2[j] * W2[j * NP + pp];
            sgate[pp] = 1.f / (1.f + expf(-s));
        }
    }
    __syncthreads();

    scale[b * NC + tid] = sattn[tid] * sgate[p];
}

// ---------------- Kernel 3: out = x * scale[row] ----------------
// REVERSE sweep (MRU-first): consume x top->bottom, so every region read is
// the most-recently-touched in L3 (pool ended at the top). nt stores keep the
// out stream from allocating/evicting. Ends at row 0 = next replay pool start.
__global__ __launch_bounds__(256) void scale_kernel(const float* __restrict__ x,
                                                    const float* __restrict__ scale,
                                                    float* __restrict__ out) {
    const v4f* xv = (const v4f*)x;
    v4f* ov = (v4f*)out;
    const size_t n = (size_t)NB * NC * (NL / 4);       // 16.7M float4
    const size_t stride = (size_t)gridDim.x * blockDim.x;  // 524288
    const int iters = (int)(n / stride);                // 32 exactly
    const size_t g = (size_t)blockIdx.x * blockDim.x + threadIdx.x;
    #pragma unroll 4
    for (int k = iters - 1; k >= 0; --k) {
        const size_t i = (size_t)k * stride + g;
        const float s = scale[i >> 10];                // NL/4 = 1024 float4 per row
        v4f v = xv[i];
        v *= s;
        __builtin_nontemporal_store(v, &ov[i]);
    }
}

extern "C" void kernel_launch(void* const* d_in, const int* in_sizes, int n_in,
                              void* d_out, int out_size, void* d_ws, size_t ws_size,
                              hipStream_t stream) {
    const float* x         = (const float*)d_in[0];
    const float* conv1_w   = (const float*)d_in[1];
    const float* conv2_w   = (const float*)d_in[2];
    const float* combine_w = (const float*)d_in[3];
    const float* combine_b = (const float*)d_in[4];
    const float* ln_g      = (const float*)d_in[5];
    const float* ln_b      = (const float*)d_in[6];
    const float* W1        = (const float*)d_in[7];
    const float* b1        = (const float*)d_in[8];
    const float* W2        = (const float*)d_in[9];
    const float* b2        = (const float*)d_in[10];
    float* out = (float*)d_out;

    float* y     = (float*)d_ws;         // NB*NC floats
    float* scale = y + NB * NC;          // NB*NC floats

    pool_kernel<<<NB * NC / 4, 256, 0, stream>>>(x, y);
    attn_kernel<<<NB, 1024, 0, stream>>>(y, conv1_w, conv2_w, combine_w, combine_b,
                                         ln_g, ln_b, W1, b1, W2, b2, scale);
    scale_kernel<<<2048, 256, 0, stream>>>(x, scale, out);
}

// Round 6
// 133.308 us; speedup vs baseline: 1.0141x; 1.0141x over previous
//
#include <hip/hip_runtime.h>
#include <hip/hip_cooperative_groups.h>
#include <math.h>

namespace cg = cooperative_groups;

#define NP 8      // paths
#define ND 128    // D = c / P
#define NC 1024   // channels = NP*ND
#define NL 4096   // sequence length
#define NB 16     // batch
#define LN_EPS 1e-5f

#define NBLK 2048           // 8 blocks/CU x 256 CUs (full co-residency)
#define RPB 8               // rows per block: 16384 / 2048

typedef float v4f __attribute__((ext_vector_type(4)));

__device__ __forceinline__ void attn_math(const float* __restrict__ sy,
                                          float* __restrict__ sattn,
                                          const float* conv1_w, const float* conv2_w,
                                          const float* combine_w, const float* combine_b,
                                          int tid) {
    #pragma unroll
    for (int k = 0; k < 4; ++k) {
        const int pos = tid + 256 * k;
        const int p = pos >> 7, d = pos & 127;
        const float* rowp = sy + p * ND;
        float c1 = 0.f;
        #pragma unroll
        for (int t = 0; t < 5; ++t) {
            int dd = d + t - 2;
            float v = (dd >= 0 && dd < ND) ? rowp[dd] : 0.f;
            c1 += conv1_w[p * 5 + t] * v;
        }
        float c2 = 0.f;
        #pragma unroll
        for (int t = 0; t < 9; ++t) {
            int dd = d + t - 4;
            float v = (dd >= 0 && dd < ND) ? rowp[dd] : 0.f;
            c2 += conv2_w[p * 9 + t] * v;
        }
        const float z = combine_w[0] * c1 + combine_w[1] * c2 + combine_b[0];
        sattn[pos] = 1.f / (1.f + expf(-z));
    }
}

__device__ __forceinline__ void gate_math(const float* __restrict__ scross,
                                          float* __restrict__ sgate,
                                          const float* ln_g, const float* ln_b,
                                          const float* W1, const float* b1,
                                          const float* W2, const float* b2) {
    float cross[NP];
    #pragma unroll
    for (int pp = 0; pp < NP; ++pp) cross[pp] = scross[pp];
    float mu = 0.f;
    #pragma unroll
    for (int pp = 0; pp < NP; ++pp) mu += cross[pp];
    mu *= (1.f / NP);
    float var = 0.f;
    #pragma unroll
    for (int pp = 0; pp < NP; ++pp) { float dl = cross[pp] - mu; var += dl * dl; }
    var *= (1.f / NP);
    const float inv = rsqrtf(var + LN_EPS);
    float h[NP];
    #pragma unroll
    for (int pp = 0; pp < NP; ++pp)
        h[pp] = (cross[pp] - mu) * inv * ln_g[pp] + ln_b[pp];
    float h2[2 * NP];
    for (int j = 0; j < 2 * NP; ++j) {
        float s = b1[j];
        #pragma unroll
        for (int pp = 0; pp < NP; ++pp) s += h[pp] * W1[pp * (2 * NP) + j];
        h2[j] = 0.5f * s * (1.f + erff(s * 0.70710678118654752f));  // exact GELU
    }
    for (int pp = 0; pp < NP; ++pp) {
        float s = b2[pp];
        #pragma unroll
        for (int j = 0; j < 2 * NP; ++j) s += h2[j] * W2[j * NP + pp];
        sgate[pp] = 1.f / (1.f + expf(-s));
    }
}

// ================= Fused cooperative kernel =================
// Each block owns RPB=8 consecutive rows (same batch, same path).
// Phase 1: load rows into REGISTERS, pool -> y.   [x read once]
// grid sync.
// Phase 2: redundantly per block: attn over batch's 1024 channels (from y),
//          per-path means, LN+MLP+gate (thread 0).
// Phase 3: scale register-resident rows, nt-store to out.
__global__ __launch_bounds__(256, 8) void fused_kernel(
    const float* __restrict__ x, float* __restrict__ y,
    const float* __restrict__ conv1_w, const float* __restrict__ conv2_w,
    const float* __restrict__ combine_w, const float* __restrict__ combine_b,
    const float* __restrict__ ln_g, const float* __restrict__ ln_b,
    const float* __restrict__ W1, const float* __restrict__ b1,
    const float* __restrict__ W2, const float* __restrict__ b2,
    float* __restrict__ out)
{
    const int tid  = threadIdx.x;
    const int row0 = blockIdx.x * RPB;          // first of 8 rows
    const int b    = row0 >> 10;                // batch
    const int p0   = (row0 & (NC - 1)) >> 7;    // path (same for all 8 rows)

    __shared__ float sred[RPB][4];
    __shared__ float sy[NC];
    __shared__ float sattn[NC];
    __shared__ float scross[NP];
    __shared__ float sgate[NP];

    v4f xd[RPB][4];
    const v4f* xb = (const v4f*)x + (size_t)row0 * (NL / 4);
    v4f* ob       = (v4f*)out    + (size_t)row0 * (NL / 4);

    // ---- Phase 1: load + pool ----
    #pragma unroll
    for (int r = 0; r < RPB; ++r) {
        float ps = 0.f;
        #pragma unroll
        for (int k = 0; k < 4; ++k) {
            xd[r][k] = xb[(size_t)r * (NL / 4) + tid + 256 * k];
            ps += xd[r][k].x + xd[r][k].y + xd[r][k].z + xd[r][k].w;
        }
        #pragma unroll
        for (int off = 32; off; off >>= 1) ps += __shfl_down(ps, off, 64);
        if ((tid & 63) == 0) sred[r][tid >> 6] = ps;
    }
    __syncthreads();
    if (tid < RPB)
        y[row0 + tid] = (sred[tid][0] + sred[tid][1] + sred[tid][2] + sred[tid][3]) * (1.f / NL);
    __threadfence();            // device-scope release of y (cross-XCD)
    cg::this_grid().sync();

    // ---- Phase 2: attn + gate for this block's batch (redundant per block) ----
    #pragma unroll
    for (int k = 0; k < 4; ++k) sy[tid + 256 * k] = y[b * NC + tid + 256 * k];
    __syncthreads();
    attn_math(sy, sattn, conv1_w, conv2_w, combine_w, combine_b, tid);
    __syncthreads();
    if (tid < NP) {
        float s = 0.f;
        for (int d = 0; d < ND; ++d) s += sattn[tid * ND + d];
        scross[tid] = s * (1.f / ND);
    }
    __syncthreads();
    if (tid == 0) gate_math(scross, sgate, ln_g, ln_b, W1, b1, W2, b2);
    __syncthreads();

    // ---- Phase 3: scale from registers, stream out ----
    const float g = sgate[p0];
    #pragma unroll
    for (int r = 0; r < RPB; ++r) {
        const float s = sattn[(row0 & (NC - 1)) + r] * g;
        #pragma unroll
        for (int k = 0; k < 4; ++k) {
            v4f v = xd[r][k] * s;
            __builtin_nontemporal_store(v, &ob[(size_t)r * (NL / 4) + tid + 256 * k]);
        }
    }
}

// ================= Fallback path (R4 kernels) =================
__global__ __launch_bounds__(256) void pool_kernel(const float* __restrict__ x,
                                                   float* __restrict__ y) {
    const int wid  = threadIdx.x >> 6;
    const int lane = threadIdx.x & 63;
    const int row  = blockIdx.x * 4 + wid;
    const v4f* xr = (const v4f*)(x + (size_t)row * NL);
    float s = 0.f;
    #pragma unroll
    for (int i = 0; i < 16; ++i) {
        v4f v = xr[lane + i * 64];
        s += v.x + v.y + v.z + v.w;
    }
    #pragma unroll
    for (int off = 32; off; off >>= 1) s += __shfl_down(s, off, 64);
    if (lane == 0) y[row] = s * (1.f / NL);
}

__global__ __launch_bounds__(1024) void attn_kernel(
    const float* __restrict__ y,
    const float* __restrict__ conv1_w, const float* __restrict__ conv2_w,
    const float* __restrict__ combine_w, const float* __restrict__ combine_b,
    const float* __restrict__ ln_g, const float* __restrict__ ln_b,
    const float* __restrict__ W1, const float* __restrict__ b1,
    const float* __restrict__ W2, const float* __restrict__ b2,
    float* __restrict__ scale)
{
    const int b = blockIdx.x;
    const int tid = threadIdx.x;
    const int p = tid >> 7;
    const int d = tid & 127;

    __shared__ float sy[NC];
    __shared__ float sattn[NC];
    __shared__ float sred[16];
    __shared__ float sgate[NP];

    sy[tid] = y[b * NC + tid];
    __syncthreads();

    const float* rowp = sy + p * ND;
    float c1 = 0.f;
    #pragma unroll
    for (int t = 0; t < 5; ++t) {
        int dd = d + t - 2;
        float v = (dd >= 0 && dd < ND) ? rowp[dd] : 0.f;
        c1 += conv1_w[p * 5 + t] * v;
    }
    float c2 = 0.f;
    #pragma unroll
    for (int t = 0; t < 9; ++t) {
        int dd = d + t - 4;
        float v = (dd >= 0 && dd < ND) ? rowp[dd] : 0.f;
        c2 += conv2_w[p * 9 + t] * v;
    }
    const float z = combine_w[0] * c1 + combine_w[1] * c2 + combine_b[0];
    const float a = 1.f / (1.f + expf(-z));
    sattn[tid] = a;

    float r = a;
    #pragma unroll
    for (int off = 32; off; off >>= 1) r += __shfl_down(r, off, 64);
    const int lane = tid & 63, wid = tid >> 6;
    if (lane == 0) sred[wid] = r;
    __syncthreads();

    if (tid == 0) {
        float scross[NP];
        #pragma unroll
        for (int pp = 0; pp < NP; ++pp)
            scross[pp] = (sred[2 * pp] + sred[2 * pp + 1]) * (1.f / ND);
        gate_math(scross, sgate, ln_g, ln_b, W1, b1, W2, b2);
    }
    __syncthreads();

    scale[b * NC + tid] = sattn[tid] * sgate[p];
}

__global__ __launch_bounds__(256) void scale_kernel(const float* __restrict__ x,
                                                    const float* __restrict__ scale,
                                                    float* __restrict__ out) {
    const v4f* xv = (const v4f*)x;
    v4f* ov = (v4f*)out;
    const size_t n = (size_t)NB * NC * (NL / 4);
    const size_t stride = (size_t)gridDim.x * blockDim.x;
    for (size_t i = (size_t)blockIdx.x * blockDim.x + threadIdx.x; i < n; i += stride) {
        const float s = scale[i >> 10];
        v4f v = xv[i];
        v *= s;
        __builtin_nontemporal_store(v, &ov[i]);
    }
}

extern "C" void kernel_launch(void* const* d_in, const int* in_sizes, int n_in,
                              void* d_out, int out_size, void* d_ws, size_t ws_size,
                              hipStream_t stream) {
    const float* x         = (const float*)d_in[0];
    const float* conv1_w   = (const float*)d_in[1];
    const float* conv2_w   = (const float*)d_in[2];
    const float* combine_w = (const float*)d_in[3];
    const float* combine_b = (const float*)d_in[4];
    const float* ln_g      = (const float*)d_in[5];
    const float* ln_b      = (const float*)d_in[6];
    const float* W1        = (const float*)d_in[7];
    const float* b1        = (const float*)d_in[8];
    const float* W2        = (const float*)d_in[9];
    const float* b2        = (const float*)d_in[10];
    float* out = (float*)d_out;

    float* y     = (float*)d_ws;         // NB*NC floats
    float* scale = y + NB * NC;          // NB*NC floats (fallback only)

    int nb = 0;
    hipOccupancyMaxActiveBlocksPerMultiprocessor(&nb, fused_kernel, 256, 0);
    if (nb >= NBLK / 256) {
        void* args[] = { (void*)&x, (void*)&y,
                         (void*)&conv1_w, (void*)&conv2_w,
                         (void*)&combine_w, (void*)&combine_b,
                         (void*)&ln_g, (void*)&ln_b,
                         (void*)&W1, (void*)&b1, (void*)&W2, (void*)&b2,
                         (void*)&out };
        hipLaunchCooperativeKernel((const void*)fused_kernel, dim3(NBLK), dim3(256),
                                   args, 0, stream);
    } else {
        pool_kernel<<<NB * NC / 4, 256, 0, stream>>>(x, y);
        attn_kernel<<<NB, 1024, 0, stream>>>(y, conv1_w, conv2_w, combine_w, combine_b,
                                             ln_g, ln_b, W1, b1, W2, b2, scale);
        scale_kernel<<<2048, 256, 0, stream>>>(x, scale, out);
    }
}